// Round 4
// baseline (119.755 us; speedup 1.0000x reference)
//
#include <hip/hip_runtime.h>
#include <cstdint>
#include <cmath>

// QuantumLatentLayer: out[b,q] = cos(a)*cos(theta_q) - sin(a)*(cos(phi_q)*sin(theta_q))
//                     a = sum_l latent[b,l]*W[q,l] + b_q
// M=32768, K=2048, N=24. HBM floor ~39 us @ 7 TB/s; VALU floor ~21 us.
//
// R2 lesson: W-from-LDS dominates the DS pipe (96/128 DS insts were W
// broadcasts). R3 lesson: global_load_lds has NO compiler-inserted wait
// before ds_read without a barrier -> must wait explicitly (R3 NaN'd).
// v4: lane = row (8 ds_read_b128/chunk/wave); W read at wave-uniform
// addresses -> s_load/SGPR operands; per-chunk s_waitcnt vmcnt(0) placed
// BEFORE next-chunk stage issue: correct regardless of W scalarization,
// and the drained loads were issued one full compute-phase (~640ns) ago,
// so the stall is ~0. Latency hiding: 2 blocks/CU.

#define NQ 24
#define LDIM 2048
#define BATCH 32768
#define KC 32             // k-chunk (floats) per buffer
#define BLK_ROWS 64       // rows per block == lanes per wave
#define KSPAN 512         // k range per wave (4-way k split)
#define NCHUNK (KSPAN / KC)   // 16

typedef const __attribute__((address_space(1))) void* gas_t;
typedef __attribute__((address_space(3))) void* las_t;

__device__ __forceinline__ void gload_lds16(const float* g, float* l) {
    __builtin_amdgcn_global_load_lds((gas_t)g, (las_t)l, 16, 0, 0);
}

// Stage latent tile [64 rows][KC=32 floats] with XOR-swizzled SOURCE (m173):
// linear LDS holds global slot g of row r at slot g^(r&7) (16B slots).
// 8 insts x 1024 B; inst i covers rows 8i..8i+7.
__device__ __forceinline__ void stage_lat(const float* src, float* ldst, int lane) {
    const int swz  = (((lane & 7) ^ ((lane >> 3) & 7)) << 2); // float offset
    const int rsub = lane >> 3;
    #pragma unroll
    for (int i = 0; i < 8; i++)
        gload_lds16(src + (size_t)(i * 8 + rsub) * LDIM + swz, ldst + i * 256);
}

// Lane owns row = lane; 24 qubits; W via wave-uniform loads (-> s_load).
// Per chunk: 8 ds_read_b128 (own row, swizzle-corrected), 768 FMA.
__device__ __forceinline__ void compute_chunk(const float* __restrict__ lbuf,
                                              const float* __restrict__ wk,
                                              int lane, float (&acc)[NQ]) {
    const int rbase = lane * KC;
    const int sw    = lane & 7;
    #pragma unroll
    for (int g = 0; g < KC / 4; g++) {
        float4 lv = *(const float4*)(lbuf + rbase + 4 * (g ^ sw));
        #pragma unroll
        for (int j = 0; j < 4; j++) {
            const float a = ((const float*)&lv)[j];
            const float* wp = wk + (g * 4 + j) * NQ;   // wave-uniform address
            #pragma unroll
            for (int q = 0; q < NQ; q++)
                acc[q] = fmaf(a, wp[q], acc[q]);
        }
    }
}

__global__ __launch_bounds__(256, 2) void qll_main(
    const float* __restrict__ latent,
    const float* __restrict__ wt,    // [LDIM][NQ]
    const float* __restrict__ bvec,  // [NQ]
    const float* __restrict__ ctv,   // [NQ] cos(theta)
    const float* __restrict__ csv,   // [NQ] cos(phi)*sin(theta)
    float* __restrict__ out)
{
    __shared__ __align__(16) float lat_lds[4][2][BLK_ROWS * KC]; // 64 KB

    const int tid  = threadIdx.x;
    const int wave = tid >> 6;
    const int lane = tid & 63;
    const int kq   = __builtin_amdgcn_readfirstlane(wave);  // k-quarter, uniform

    const int row0 = blockIdx.x * BLK_ROWS;
    const float* lsrc  = latent + (size_t)row0 * LDIM + (size_t)kq * KSPAN;
    const float* wbase = wt + (size_t)kq * KSPAN * NQ;

    float* lb0 = &lat_lds[wave][0][0];
    float* lb1 = &lat_lds[wave][1][0];

    float acc[NQ];
    #pragma unroll
    for (int q = 0; q < NQ; q++) acc[q] = 0.0f;

    stage_lat(lsrc, lb0, lane);  // chunk 0 -> buf0

    #pragma unroll 1
    for (int c = 0; c < NCHUNK; c++) {
        // Drain ALL outstanding VMEM: guarantees buf[c] is fully written.
        // Placed BEFORE the next stage issue, so what we drain was issued one
        // compute-phase ago (stall ~0), and correctness doesn't depend on how
        // many VMEM insts the W loads turned into.
        asm volatile("s_waitcnt vmcnt(0)" ::: "memory");
        if (c + 1 < NCHUNK)
            stage_lat(lsrc + (c + 1) * KC, ((c & 1) == 0) ? lb1 : lb0, lane);
        compute_chunk(((c & 1) == 0) ? lb0 : lb1, wbase + (size_t)c * KC * NQ,
                      lane, acc);
    }

    // k-quarter partials -> this wave's dead buf0 (last chunk computed from
    // buf1, buf0's last read was chunk NCHUNK-2) as red[64][24].
    {
        float* dst = lb0 + lane * NQ;           // 96 B stride, 16B-aligned
        #pragma unroll
        for (int v = 0; v < 6; v++)
            ((float4*)dst)[v] = make_float4(acc[4*v], acc[4*v+1], acc[4*v+2], acc[4*v+3]);
    }
    __syncthreads();

    // epilogue: 64 rows x 24 q = 1536 outputs, 6 consecutive per thread.
    // flat = tid*6 + i; q = (tid&3)*6 + i  (exact, no modulo).
    {
        const int qb    = (tid & 3) * 6;
        const int flat0 = tid * 6;
        float* op = out + (size_t)blockIdx.x * (BLK_ROWS * NQ) + flat0;
        #pragma unroll
        for (int v = 0; v < 3; v++) {
            float2 o;
            #pragma unroll
            for (int e = 0; e < 2; e++) {
                int i = v * 2 + e;
                int q = qb + i;
                int flat = flat0 + i;
                float a = lat_lds[0][0][flat] + lat_lds[1][0][flat]
                        + lat_lds[2][0][flat] + lat_lds[3][0][flat] + bvec[q];
                float s, co;
                __sincosf(a, &s, &co);
                ((float*)&o)[e] = co * ctv[q] - s * csv[q];
            }
            *(float2*)(op + v * 2) = o;
        }
    }
}

// Prep: Wt[k][q] = W[q][k]; ctcs[0..23]=cos(theta), ctcs[24..47]=cos(phi)*sin(theta)
__global__ __launch_bounds__(256) void qll_prep(
    const float* __restrict__ W, const float* __restrict__ params,
    float* __restrict__ wt, float* __restrict__ ctcs)
{
    int idx = blockIdx.x * 256 + threadIdx.x;
    if (idx < LDIM * NQ) {
        int q = idx % NQ;
        int k = idx / NQ;
        wt[idx] = W[q * LDIM + k];
    }
    if (idx < NQ) {
        float phi = params[3 * idx + 0];
        float th  = params[3 * idx + 1];
        ctcs[idx]      = cosf(th);
        ctcs[NQ + idx] = cosf(phi) * sinf(th);
    }
}

extern "C" void kernel_launch(void* const* d_in, const int* in_sizes, int n_in,
                              void* d_out, int out_size, void* d_ws, size_t ws_size,
                              hipStream_t stream) {
    (void)in_sizes; (void)n_in; (void)out_size; (void)ws_size;
    const float* latent = (const float*)d_in[0];
    const float* W      = (const float*)d_in[1];
    const float* bvec   = (const float*)d_in[2];
    const float* params = (const float*)d_in[3];
    float* out  = (float*)d_out;
    float* wt   = (float*)d_ws;              // LDIM*NQ floats
    float* ctcs = wt + LDIM * NQ;            // 2*NQ floats

    hipLaunchKernelGGL(qll_prep, dim3((LDIM * NQ + 255) / 256), dim3(256), 0, stream,
                       W, params, wt, ctcs);
    hipLaunchKernelGGL(qll_main, dim3(BATCH / BLK_ROWS), dim3(256), 0, stream,
                       latent, wt, bvec, ctcs, ctcs + NQ, out);
}